// Round 7
// baseline (105.896 us; speedup 1.0000x reference)
//
#include <hip/hip_runtime.h>
#include <hip/hip_cooperative_groups.h>

namespace cg = cooperative_groups;

typedef unsigned int u32;
typedef unsigned short u16;
typedef float f32x16 __attribute__((ext_vector_type(16)));
typedef __bf16 bf16x8 __attribute__((ext_vector_type(8)));
union BF8 { u32 w[4]; bf16x8 v; };

#define DEVI static __device__ __forceinline__
DEVI u32 pk_bf16(float lo, float hi) {
  u32 r;
  asm("v_cvt_pk_bf16_f32 %0, %1, %2" : "=v"(r) : "v"(lo), "v"(hi));
  return r;
}
DEVI u16 bf1(float x) { return (u16)(pk_bf16(x, 0.0f) & 0xffffu); }

// ---- workspace byte offsets ----
#define WB_WREP  0        // 27*32*64 bf16 = 110592
#define WB_QS    131072   // 8192*16 bf16
#define WB_K     393216   // 8192*16 bf16
#define WB_VT    655360   // 16*8192 bf16
#define WB_FUS   917504   // 8192*64 bf16 = 1 MB: [n][0..31]=x, [n][32..63]=ctx (ends 1966080)

struct Params {
  const float *x;
  const float *wq1, *sq1, *bq1, *wq2, *sq2, *bq2;
  const float *wk1, *sk1, *bk1, *wk2, *sk2, *bk2;
  const float *wv, *sv, *bv, *wo, *so, *bo;
  const float *wbot, *sbot, *bbot;
  u16 *qs, *kbm, *vt, *fus, *wrep;
  float *out;
};

// One cooperative kernel: 256 blocks x 1024 threads (16 waves, 1 block/CU).
// Phase 1: qkv (waves 0-3) + wrep repack (upper threads).  grid.sync()
// Phase 2: flash attention, 16 waves x 512 keys + LDS reduce + out-proj.  grid.sync()
// Phase 3: 3x3x3 conv, 54 units over 16 waves + LDS reduce + bias + LeakyReLU.
__global__ __launch_bounds__(1024) void k_fused(Params p) {
  __shared__ float SH[16384];   // 64 KB, aliased per phase
  const int tid = threadIdx.x;
  const int bid = blockIdx.x;
  const int n0 = bid << 5;
  cg::grid_group grid = cg::this_grid();

  // ======================= PHASE 1: qkv + repack =======================
  {
    // pool phase A: per-d channel sums (threads 0-255)
    if (tid < 256) {
      const int d = n0 >> 9;
      const int c = tid >> 3, part = tid & 7;
      const float4* xp = (const float4*)(p.x + (c << 13) + (d << 9));
      float s = 0.f;
#pragma unroll
      for (int i = 0; i < 16; ++i) {
        const float4 v4 = xp[part + (i << 3)];
        s += v4.x + v4.y + v4.z + v4.w;
      }
      SH[1088 + (c << 3) + part] = s;   // P8[c][part]
    }
    // repack (threads 256..471): 216 wrep elements per block
    if (tid >= 256 && tid < 472) {
      const int idx = bid * 216 + (tid - 256);
      const int tap = idx >> 11, rem = idx & 2047, o = rem >> 6, i = rem & 63;
      p.wrep[idx] = bf1(p.wbot[(o * 64 + i) * 27 + tap] * p.sbot[o]);
    }
    __syncthreads();
    if (tid < 32) {
      float s = 0.f;
#pragma unroll
      for (int j = 0; j < 8; ++j) s += SH[1088 + (tid << 3) + j];
      SH[1344 + tid] = s * (1.0f / 512.0f);   // xgs
    }
    __syncthreads();
    if (tid < 256) {
      const int nl = tid & 31, g = tid >> 5;
      const int n = n0 + nl;
      const int r0 = 2 * g, r1 = r0 + 1;
      float xr[32], xgv[32];
#pragma unroll
      for (int c = 0; c < 32; ++c) xr[c] = p.x[(c << 13) + n];
#pragma unroll
      for (int c = 0; c < 32; ++c) xgv[c] = SH[1344 + c];

      const float4* wq1f = (const float4*)p.wq1;
      const float4* wk1f = (const float4*)p.wk1;
      const float4* wvf  = (const float4*)p.wv;
      float dq0 = 0.f, dq1 = 0.f, dk0 = 0.f, dk1 = 0.f, dv0 = 0.f, dv1 = 0.f;
#pragma unroll
      for (int c4 = 0; c4 < 8; ++c4) {
        const float4 wa = wq1f[r0 * 8 + c4], wb = wq1f[r1 * 8 + c4];
        dq0 += wa.x * xr[4*c4+0] + wa.y * xr[4*c4+1] + wa.z * xr[4*c4+2] + wa.w * xr[4*c4+3];
        dq1 += wb.x * xr[4*c4+0] + wb.y * xr[4*c4+1] + wb.z * xr[4*c4+2] + wb.w * xr[4*c4+3];
      }
#pragma unroll
      for (int c4 = 0; c4 < 8; ++c4) {   // key_feats channels 0..31 = xg broadcast
        const float4 ka = wk1f[r0 * 16 + c4], kb = wk1f[r1 * 16 + c4];
        dk0 += ka.x * xgv[4*c4+0] + ka.y * xgv[4*c4+1] + ka.z * xgv[4*c4+2] + ka.w * xgv[4*c4+3];
        dk1 += kb.x * xgv[4*c4+0] + kb.y * xgv[4*c4+1] + kb.z * xgv[4*c4+2] + kb.w * xgv[4*c4+3];
        const float4 va = wvf[r0 * 16 + c4], vb = wvf[r1 * 16 + c4];
        dv0 += va.x * xgv[4*c4+0] + va.y * xgv[4*c4+1] + va.z * xgv[4*c4+2] + va.w * xgv[4*c4+3];
        dv1 += vb.x * xgv[4*c4+0] + vb.y * xgv[4*c4+1] + vb.z * xgv[4*c4+2] + vb.w * xgv[4*c4+3];
      }
#pragma unroll
      for (int c4 = 0; c4 < 8; ++c4) {   // key_feats channels 32..63 = x
        const float4 ka = wk1f[r0 * 16 + 8 + c4], kb = wk1f[r1 * 16 + 8 + c4];
        dk0 += ka.x * xr[4*c4+0] + ka.y * xr[4*c4+1] + ka.z * xr[4*c4+2] + ka.w * xr[4*c4+3];
        dk1 += kb.x * xr[4*c4+0] + kb.y * xr[4*c4+1] + kb.z * xr[4*c4+2] + kb.w * xr[4*c4+3];
        const float4 va = wvf[r0 * 16 + 8 + c4], vb = wvf[r1 * 16 + 8 + c4];
        dv0 += va.x * xr[4*c4+0] + va.y * xr[4*c4+1] + va.z * xr[4*c4+2] + va.w * xr[4*c4+3];
        dv1 += vb.x * xr[4*c4+0] + vb.y * xr[4*c4+1] + vb.z * xr[4*c4+2] + vb.w * xr[4*c4+3];
      }
      const float hq0 = fmaxf(dq0 * p.sq1[r0] + p.bq1[r0], 0.f);
      const float hq1 = fmaxf(dq1 * p.sq1[r1] + p.bq1[r1], 0.f);
      const float hk0 = fmaxf(dk0 * p.sk1[r0] + p.bk1[r0], 0.f);
      const float hk1 = fmaxf(dk1 * p.sk1[r1] + p.bk1[r1], 0.f);
      const float hv0 = fmaxf(dv0 * p.sv[r0] + p.bv[r0], 0.f);
      const float hv1 = fmaxf(dv1 * p.sv[r1] + p.bv[r1], 0.f);
      SH[nl * 17 + r0] = hq0;       SH[nl * 17 + r1] = hq1;        // H[0]
      SH[544 + nl * 17 + r0] = hk0; SH[544 + nl * 17 + r1] = hk1;  // H[1]
      p.vt[(r0 << 13) + n] = bf1(hv0);
      p.vt[(r1 << 13) + n] = bf1(hv1);
      const int c0 = g << 2;   // x channels into the fused conv-input buffer
      *(u32*)(p.fus + (n << 6) + c0)     = pk_bf16(xr[c0],     xr[c0 + 1]);
      *(u32*)(p.fus + (n << 6) + c0 + 2) = pk_bf16(xr[c0 + 2], xr[c0 + 3]);
    }
    __syncthreads();
    if (tid < 256) {
      const int nl = tid & 31, g = tid >> 5;
      const int n = n0 + nl;
      const int r0 = 2 * g, r1 = r0 + 1;
      float eq0 = 0.f, eq1 = 0.f, ek0 = 0.f, ek1 = 0.f;
#pragma unroll
      for (int j = 0; j < 16; ++j) {
        const float hq = SH[nl * 17 + j], hk = SH[544 + nl * 17 + j];
        eq0 += p.wq2[r0 * 16 + j] * hq;
        eq1 += p.wq2[r1 * 16 + j] * hq;
        ek0 += p.wk2[r0 * 16 + j] * hk;
        ek1 += p.wk2[r1 * 16 + j] * hk;
      }
      const float SC = 0.36067376022224085f;  // CT^-0.5 * log2(e), folded into q
      const float q0 = fmaxf(eq0 * (p.sq2[r0] * SC) + p.bq2[r0] * SC, 0.f);
      const float q1 = fmaxf(eq1 * (p.sq2[r1] * SC) + p.bq2[r1] * SC, 0.f);
      const float k0 = fmaxf(ek0 * p.sk2[r0] + p.bk2[r0], 0.f);
      const float k1 = fmaxf(ek1 * p.sk2[r1] + p.bk2[r1], 0.f);
      *(u32*)(p.qs  + (n << 4) + r0) = pk_bf16(q0, q1);
      *(u32*)(p.kbm + (n << 4) + r0) = pk_bf16(k0, k1);
    }
  }

  grid.sync();

  // ======================= PHASE 2: attention =======================
  {
    const int w = tid >> 6, lane = tid & 63;
    const int l31 = lane & 31, h = lane >> 5;
    const int qb = bid;

    const bf16x8 qf = *(const bf16x8*)(p.qs + (((qb << 5) + l31) << 4) + (h << 3));
    f32x16 acc_a, acc_b, z;
#pragma unroll
    for (int i = 0; i < 16; ++i) { acc_a[i] = 0.f; acc_b[i] = 0.f; z[i] = 0.f; }

    const u32 fill = (l31 == 16) ? 0x3F803F80u : 0u;  // ones-column: denominator in col 16
    const int kb0 = w << 9;   // 512 keys per wave
    const bool vlane = (l31 < 16);
    const u16* vrow = p.vt + (l31 << 13) + (h << 3);

    bf16x8 kf_c = *(const bf16x8*)(p.kbm + ((kb0 + l31) << 4) + (h << 3));
    BF8 V1c, V2c;
#pragma unroll
    for (int j2 = 0; j2 < 4; ++j2) { V1c.w[j2] = fill; V2c.w[j2] = fill; }
    if (vlane) {
      V1c.v = *(const bf16x8*)(vrow + kb0);
      V2c.v = *(const bf16x8*)(vrow + kb0 + 16);
    }

#pragma unroll
    for (int t = 0; t < 16; ++t) {
      const bf16x8 kf = kf_c;
      const BF8 V1 = V1c, V2 = V2c;
      if (t < 15) {   // prefetch tile t+1 while computing tile t
        const int kbn = kb0 + ((t + 1) << 5);
        kf_c = *(const bf16x8*)(p.kbm + ((kbn + l31) << 4) + (h << 3));
        if (vlane) {
          V1c.v = *(const bf16x8*)(vrow + kbn);
          V2c.v = *(const bf16x8*)(vrow + kbn + 16);
        }
      }
      const f32x16 st = __builtin_amdgcn_mfma_f32_32x32x16_bf16(kf, qf, z, 0, 0, 0);
      float pe[16];
#pragma unroll
      for (int r = 0; r < 16; ++r) pe[r] = __builtin_amdgcn_exp2f(st[r]);
      u32 a0 = pk_bf16(pe[0],  pe[1]),  a1 = pk_bf16(pe[2],  pe[3]);
      u32 a2 = pk_bf16(pe[4],  pe[5]),  a3 = pk_bf16(pe[6],  pe[7]);
      u32 b0 = pk_bf16(pe[8],  pe[9]),  b1 = pk_bf16(pe[10], pe[11]);
      u32 b2 = pk_bf16(pe[12], pe[13]), b3 = pk_bf16(pe[14], pe[15]);
      asm("v_permlane32_swap_b32 %0, %1" : "+v"(a0), "+v"(a2));
      asm("v_permlane32_swap_b32 %0, %1" : "+v"(a1), "+v"(a3));
      asm("v_permlane32_swap_b32 %0, %1" : "+v"(b0), "+v"(b2));
      asm("v_permlane32_swap_b32 %0, %1" : "+v"(b1), "+v"(b3));
      BF8 A1, A2;
      A1.w[0] = a0; A1.w[1] = a1; A1.w[2] = a2; A1.w[3] = a3;
      A2.w[0] = b0; A2.w[1] = b1; A2.w[2] = b2; A2.w[3] = b3;
      __builtin_amdgcn_s_setprio(1);
      acc_a = __builtin_amdgcn_mfma_f32_32x32x16_bf16(A1.v, V1.v, acc_a, 0, 0, 0);
      acc_b = __builtin_amdgcn_mfma_f32_32x32x16_bf16(A2.v, V2.v, acc_b, 0, 0, 0);
      __builtin_amdgcn_s_setprio(0);
    }
    if (l31 < 17) {
#pragma unroll
      for (int r = 0; r < 16; ++r) {
        const int row = (r & 3) + ((r >> 2) << 3) + (h << 2);
        SH[w * 544 + row * 17 + l31] = acc_a[r] + acc_b[r];
      }
    }
    __syncthreads();
    if (tid < 544) {
      float s0 = 0.f;
#pragma unroll
      for (int w2 = 0; w2 < 16; ++w2) s0 += SH[w2 * 544 + tid];
      SH[tid] = s0;
    }
    __syncthreads();
    if (tid < 512) {
      const int row = tid >> 4;
      const int o0 = (tid & 15) << 1, o1 = o0 + 1;
      const float inv = 1.0f / SH[row * 17 + 16];
      float d0 = 0.f, d1 = 0.f;
#pragma unroll
      for (int c = 0; c < 16; ++c) {
        const float cv = SH[row * 17 + c];
        d0 += p.wo[o0 * 16 + c] * cv;
        d1 += p.wo[o1 * 16 + c] * cv;
      }
      const float y0 = fmaxf(p.bo[o0] + p.so[o0] * d0 * inv, 0.f);
      const float y1 = fmaxf(p.bo[o1] + p.so[o1] * d1 * inv, 0.f);
      *(u32*)(p.fus + (((qb << 5) + row) << 6) + 32 + o0) = pk_bf16(y0, y1);
    }
  }

  grid.sync();

  // ======================= PHASE 3: 3x3x3 conv =======================
  {
    const int wv = tid >> 6, lane = tid & 63;
    const int l31 = lane & 31, h = lane >> 5;
    const int dz = n0 >> 9, hy = (n0 >> 5) & 15;
    f32x16 acc0, acc1;
#pragma unroll
    for (int i = 0; i < 16; ++i) { acc0[i] = 0.f; acc1[i] = 0.f; }
    const int ulo = (wv * 54) >> 4, uhi = ((wv + 1) * 54) >> 4;  // 3-4 units/wave

    const u16* bp_c; const u16* wp_c; bool ok_c;
    {
      const int tap = ulo >> 1, ch = (ulo & 1) << 1;
      const int dd = tap / 9 - 1, dh = (tap / 3) % 3 - 1, dw = tap % 3 - 1;
      ok_c = ((unsigned)(dz + dd) < 16u) & ((unsigned)(hy + dh) < 16u) &
             ((unsigned)(l31 + dw) < 32u);
      const int nn = n0 + dd * 512 + dh * 32 + dw + l31;
      bp_c = p.fus + (nn << 6) + (ch << 4) + (h << 3);
      wp_c = p.wrep + ((tap * 32 + l31) << 6) + (ch << 4) + (h << 3);
    }
    BF8 B0c, B1c;
    B0c.w[0] = B0c.w[1] = B0c.w[2] = B0c.w[3] = 0u;
    B1c.w[0] = B1c.w[1] = B1c.w[2] = B1c.w[3] = 0u;
    if (ok_c) { B0c.v = *(const bf16x8*)bp_c; B1c.v = *(const bf16x8*)(bp_c + 16); }

    for (int u = ulo; u < uhi; ++u) {
      const BF8 B0 = B0c, B1 = B1c;
      const u16* wp = wp_c;
      if (u + 1 < uhi) {   // prefetch next unit's B operands
        const int un = u + 1;
        const int tap = un >> 1, ch = (un & 1) << 1;
        const int dd = tap / 9 - 1, dh = (tap / 3) % 3 - 1, dw = tap % 3 - 1;
        const bool ok = ((unsigned)(dz + dd) < 16u) & ((unsigned)(hy + dh) < 16u) &
                        ((unsigned)(l31 + dw) < 32u);
        const int nn = n0 + dd * 512 + dh * 32 + dw + l31;
        const u16* bp = p.fus + (nn << 6) + (ch << 4) + (h << 3);
        wp_c = p.wrep + ((tap * 32 + l31) << 6) + (ch << 4) + (h << 3);
        B0c.w[0] = B0c.w[1] = B0c.w[2] = B0c.w[3] = 0u;
        B1c.w[0] = B1c.w[1] = B1c.w[2] = B1c.w[3] = 0u;
        if (ok) { B0c.v = *(const bf16x8*)bp; B1c.v = *(const bf16x8*)(bp + 16); }
      }
      const bf16x8 af0 = *(const bf16x8*)wp;
      const bf16x8 af1 = *(const bf16x8*)(wp + 16);
      __builtin_amdgcn_s_setprio(1);
      acc0 = __builtin_amdgcn_mfma_f32_32x32x16_bf16(af0, B0.v, acc0, 0, 0, 0);
      acc1 = __builtin_amdgcn_mfma_f32_32x32x16_bf16(af1, B1.v, acc1, 0, 0, 0);
      __builtin_amdgcn_s_setprio(0);
    }
#pragma unroll
    for (int r = 0; r < 16; ++r) {
      const int row = (r & 3) + ((r >> 2) << 3) + (h << 2);
      SH[wv * 1024 + (row << 5) + l31] = acc0[r] + acc1[r];
    }
    __syncthreads();
    {
      const int row = tid >> 5;
      float yv = p.bbot[row];
#pragma unroll
      for (int w2 = 0; w2 < 16; ++w2) yv += SH[w2 * 1024 + tid];
      p.out[(row << 13) + n0 + (tid & 31)] = yv > 0.f ? yv : 0.1f * yv;
    }
  }
}

extern "C" void kernel_launch(void* const* d_in, const int* in_sizes, int n_in,
                              void* d_out, int out_size, void* d_ws, size_t ws_size,
                              hipStream_t stream) {
  (void)in_sizes; (void)n_in; (void)out_size; (void)ws_size;
  char* wsb = (char*)d_ws;
  Params hp;
  hp.x    = (const float*)d_in[0];
  hp.wq1  = (const float*)d_in[1];
  hp.sq1  = (const float*)d_in[2];
  hp.bq1  = (const float*)d_in[3];
  hp.wq2  = (const float*)d_in[4];
  hp.sq2  = (const float*)d_in[5];
  hp.bq2  = (const float*)d_in[6];
  hp.wk1  = (const float*)d_in[7];
  hp.sk1  = (const float*)d_in[8];
  hp.bk1  = (const float*)d_in[9];
  hp.wk2  = (const float*)d_in[10];
  hp.sk2  = (const float*)d_in[11];
  hp.bk2  = (const float*)d_in[12];
  hp.wv   = (const float*)d_in[13];
  hp.sv   = (const float*)d_in[14];
  hp.bv   = (const float*)d_in[15];
  hp.wo   = (const float*)d_in[16];
  hp.so   = (const float*)d_in[17];
  hp.bo   = (const float*)d_in[18];
  hp.wbot = (const float*)d_in[19];
  hp.sbot = (const float*)d_in[20];
  hp.bbot = (const float*)d_in[21];
  hp.qs   = (u16*)(wsb + WB_QS);
  hp.kbm  = (u16*)(wsb + WB_K);
  hp.vt   = (u16*)(wsb + WB_VT);
  hp.fus  = (u16*)(wsb + WB_FUS);
  hp.wrep = (u16*)(wsb + WB_WREP);
  hp.out  = (float*)d_out;

  void* kargs[] = { &hp };
  hipLaunchCooperativeKernel((const void*)k_fused, dim3(256), dim3(1024),
                             kargs, 0, stream);
}

// Round 8
// 35.578 us; speedup vs baseline: 2.9764x; 2.9764x over previous
//
#include <hip/hip_runtime.h>

typedef unsigned int u32;
typedef unsigned short u16;
typedef float f32x16 __attribute__((ext_vector_type(16)));
typedef __bf16 bf16x8 __attribute__((ext_vector_type(8)));
union BF8 { u32 w[4]; bf16x8 v; };

#define DEVI static __device__ __forceinline__
DEVI u32 pk_bf16(float lo, float hi) {
  u32 r;
  asm("v_cvt_pk_bf16_f32 %0, %1, %2" : "=v"(r) : "v"(lo), "v"(hi));
  return r;
}
DEVI u16 bf1(float x) { return (u16)(pk_bf16(x, 0.0f) & 0xffffu); }

// ---- workspace byte offsets ----
#define WB_WREP  0        // 27*32*64 bf16 = 110592
#define WB_QS    131072   // 8192*16 bf16
#define WB_K     393216   // 8192*16 bf16
#define WB_VTS   655360   // 256 tiles * 16 ct * 32 keys bf16 = 262144 B
#define WB_FUS   917504   // 8192*64 bf16 = 1 MB: [n][0..31]=x, [n][32..63]=ctx (ends 1966080)

// =============== K1: qkv (in-block pooling + inline BN fold) + wrep repack ===============
// 256 main blocks x 512 threads (2 waves/SIMD) + 14 repack blocks.
__global__ __launch_bounds__(512) void k_prep(
    const float* __restrict__ x,
    const float* __restrict__ wq1, const float* __restrict__ sq1, const float* __restrict__ bq1,
    const float* __restrict__ wq2, const float* __restrict__ sq2, const float* __restrict__ bq2,
    const float* __restrict__ wk1, const float* __restrict__ sk1, const float* __restrict__ bk1,
    const float* __restrict__ wk2, const float* __restrict__ sk2, const float* __restrict__ bk2,
    const float* __restrict__ wv,  const float* __restrict__ sv,  const float* __restrict__ bv,
    const float* __restrict__ wbot, const float* __restrict__ sbot,
    u16* __restrict__ qs, u16* __restrict__ kbm, u16* __restrict__ vts,
    u16* __restrict__ fus, u16* __restrict__ wrep) {
  const int tid = threadIdx.x;
  const int bid = blockIdx.x;
  if (bid >= 256) {
    const int rb = bid - 256;
#pragma unroll
    for (int e = 0; e < 8; ++e) {
      const int idx = rb * 4096 + tid * 8 + e;
      if (idx < 55296) {
        const int tap = idx >> 11, rem = idx & 2047, o = rem >> 6, i = rem & 63;
        wrep[idx] = bf1(wbot[(o * 64 + i) * 27 + tap] * sbot[o]);
      }
    }
    return;
  }
  __shared__ float SH[1664];   // H[0]:0..544, H[1]:544..1088, P16:1088..1600, xgs:1600..1632
  const int n0 = bid << 5;
  const int d = n0 >> 9;
  // phase A: per-d channel means (AdaptiveAvgPool over h,w); 32 ch x 16 parts
  {
    const int c = tid >> 4, part = tid & 15;
    const float4* xp = (const float4*)(x + (c << 13) + (d << 9));
    float s = 0.f;
#pragma unroll
    for (int i = 0; i < 8; ++i) {
      const float4 v4 = xp[part + (i << 4)];
      s += v4.x + v4.y + v4.z + v4.w;
    }
    SH[1088 + (c << 4) + part] = s;
  }
  __syncthreads();
  if (tid < 32) {
    float s = 0.f;
#pragma unroll
    for (int j = 0; j < 16; ++j) s += SH[1088 + (tid << 4) + j];
    SH[1600 + tid] = s * (1.0f / 512.0f);
  }
  __syncthreads();
  // phase B: first-layer projections, 1 output per thread (16 groups x 32 n)
  const int nl = tid & 31, g = tid >> 5;
  const int n = n0 + nl;
  {
    float xr[32], xgv[32];
#pragma unroll
    for (int c = 0; c < 32; ++c) xr[c] = x[(c << 13) + n];
#pragma unroll
    for (int c = 0; c < 32; ++c) xgv[c] = SH[1600 + c];

    const float4* wq1f = (const float4*)wq1;
    const float4* wk1f = (const float4*)wk1;
    const float4* wvf  = (const float4*)wv;
    float dq = 0.f, dk = 0.f, dv = 0.f;
#pragma unroll
    for (int c4 = 0; c4 < 8; ++c4) {
      const float4 wa = wq1f[g * 8 + c4];
      dq += wa.x * xr[4*c4+0] + wa.y * xr[4*c4+1] + wa.z * xr[4*c4+2] + wa.w * xr[4*c4+3];
    }
#pragma unroll
    for (int c4 = 0; c4 < 8; ++c4) {   // key_feats channels 0..31 = xg broadcast
      const float4 ka = wk1f[g * 16 + c4];
      dk += ka.x * xgv[4*c4+0] + ka.y * xgv[4*c4+1] + ka.z * xgv[4*c4+2] + ka.w * xgv[4*c4+3];
      const float4 va = wvf[g * 16 + c4];
      dv += va.x * xgv[4*c4+0] + va.y * xgv[4*c4+1] + va.z * xgv[4*c4+2] + va.w * xgv[4*c4+3];
    }
#pragma unroll
    for (int c4 = 0; c4 < 8; ++c4) {   // key_feats channels 32..63 = x
      const float4 ka = wk1f[g * 16 + 8 + c4];
      dk += ka.x * xr[4*c4+0] + ka.y * xr[4*c4+1] + ka.z * xr[4*c4+2] + ka.w * xr[4*c4+3];
      const float4 va = wvf[g * 16 + 8 + c4];
      dv += va.x * xr[4*c4+0] + va.y * xr[4*c4+1] + va.z * xr[4*c4+2] + va.w * xr[4*c4+3];
    }
    const float hq = fmaxf(dq * sq1[g] + bq1[g], 0.f);
    const float hk = fmaxf(dk * sk1[g] + bk1[g], 0.f);
    const float hv = fmaxf(dv * sv[g] + bv[g], 0.f);
    SH[nl * 17 + g] = hq;
    SH[544 + nl * 17 + g] = hk;
    // V in per-tile layout: vts[tile=bid][ct=g][key-in-tile=nl]
    vts[(bid << 9) + (g << 5) + nl] = bf1(hv);
    // x channels into the fused conv-input buffer (2 ch per thread)
    const int c0 = g << 1;
    *(u32*)(fus + (n << 6) + c0) = pk_bf16(xr[c0], xr[c0 + 1]);
  }
  __syncthreads();
  // phase C: second-layer projections, threads 0..255, 2 outputs per thread
  if (tid < 256) {
    const int nl2 = tid & 31, g2 = tid >> 5;
    const int n2 = n0 + nl2;
    const int r0 = 2 * g2, r1 = r0 + 1;
    float eq0 = 0.f, eq1 = 0.f, ek0 = 0.f, ek1 = 0.f;
#pragma unroll
    for (int j = 0; j < 16; ++j) {
      const float hq = SH[nl2 * 17 + j], hk = SH[544 + nl2 * 17 + j];
      eq0 += wq2[r0 * 16 + j] * hq;
      eq1 += wq2[r1 * 16 + j] * hq;
      ek0 += wk2[r0 * 16 + j] * hk;
      ek1 += wk2[r1 * 16 + j] * hk;
    }
    const float SC = 0.36067376022224085f;  // CT^-0.5 * log2(e), folded into q
    const float q0 = fmaxf(eq0 * (sq2[r0] * SC) + bq2[r0] * SC, 0.f);
    const float q1 = fmaxf(eq1 * (sq2[r1] * SC) + bq2[r1] * SC, 0.f);
    const float k0 = fmaxf(ek0 * sk2[r0] + bk2[r0], 0.f);
    const float k1 = fmaxf(ek1 * sk2[r1] + bk2[r1], 0.f);
    *(u32*)(qs  + (n2 << 4) + r0) = pk_bf16(q0, q1);
    *(u32*)(kbm + (n2 << 4) + r0) = pk_bf16(k0, k1);
  }
}

// =============== K2: flash attention, 16 waves x 512 keys, prefetch + dual-acc + setprio ===============
// 256 blocks (one per 32-row q-block) x 1024 threads; 4 waves/SIMD. V via per-tile coalesced layout.
__global__ __launch_bounds__(1024) void k_attn(
    const u16* __restrict__ qs, const u16* __restrict__ kbm, const u16* __restrict__ vts,
    const float* __restrict__ wo, const float* __restrict__ so, const float* __restrict__ bo,
    u16* __restrict__ fus) {
  __shared__ float R[16][32][17];   // [wave][q-row][16 ctx + denom] = 34816 B
  const int tid = threadIdx.x;
  const int w = tid >> 6, lane = tid & 63;
  const int l31 = lane & 31, h = lane >> 5;
  const int qb = blockIdx.x;

  const bf16x8 qf = *(const bf16x8*)(qs + (((qb << 5) + l31) << 4) + (h << 3));
  f32x16 acc_a, acc_b, z;
#pragma unroll
  for (int i = 0; i < 16; ++i) { acc_a[i] = 0.f; acc_b[i] = 0.f; z[i] = 0.f; }

  const u32 fill = (l31 == 16) ? 0x3F803F80u : 0u;  // ones-column: denominator rides col 16
  const int kb0 = w << 9;          // 512 keys per wave
  const int t0 = w << 4;           // first 32-key tile index
  const bool vlane = (l31 < 16);
  const u16* vbase = vts + (l31 << 5) + (h << 3);  // + tile*512 per tile

  // prologue: prefetch tile 0
  bf16x8 kf_c = *(const bf16x8*)(kbm + ((kb0 + l31) << 4) + (h << 3));
  BF8 V1c, V2c;
#pragma unroll
  for (int j2 = 0; j2 < 4; ++j2) { V1c.w[j2] = fill; V2c.w[j2] = fill; }
  if (vlane) {
    V1c.v = *(const bf16x8*)(vbase + (t0 << 9));
    V2c.v = *(const bf16x8*)(vbase + (t0 << 9) + 16);
  }

#pragma unroll
  for (int t = 0; t < 16; ++t) {
    const bf16x8 kf = kf_c;
    const BF8 V1 = V1c, V2 = V2c;
    if (t < 15) {   // prefetch tile t+1 while computing tile t
      const int kbn = kb0 + ((t + 1) << 5);
      kf_c = *(const bf16x8*)(kbm + ((kbn + l31) << 4) + (h << 3));
      if (vlane) {
        const u16* vp = vbase + ((t0 + t + 1) << 9);
        V1c.v = *(const bf16x8*)vp;
        V2c.v = *(const bf16x8*)(vp + 16);
      }
    }
    const f32x16 st = __builtin_amdgcn_mfma_f32_32x32x16_bf16(kf, qf, z, 0, 0, 0);
    float pe[16];
#pragma unroll
    for (int r = 0; r < 16; ++r) pe[r] = __builtin_amdgcn_exp2f(st[r]);
    u32 a0 = pk_bf16(pe[0],  pe[1]),  a1 = pk_bf16(pe[2],  pe[3]);
    u32 a2 = pk_bf16(pe[4],  pe[5]),  a3 = pk_bf16(pe[6],  pe[7]);
    u32 b0 = pk_bf16(pe[8],  pe[9]),  b1 = pk_bf16(pe[10], pe[11]);
    u32 b2 = pk_bf16(pe[12], pe[13]), b3 = pk_bf16(pe[14], pe[15]);
    asm("v_permlane32_swap_b32 %0, %1" : "+v"(a0), "+v"(a2));
    asm("v_permlane32_swap_b32 %0, %1" : "+v"(a1), "+v"(a3));
    asm("v_permlane32_swap_b32 %0, %1" : "+v"(b0), "+v"(b2));
    asm("v_permlane32_swap_b32 %0, %1" : "+v"(b1), "+v"(b3));
    BF8 A1, A2;
    A1.w[0] = a0; A1.w[1] = a1; A1.w[2] = a2; A1.w[3] = a3;
    A2.w[0] = b0; A2.w[1] = b1; A2.w[2] = b2; A2.w[3] = b3;
    __builtin_amdgcn_s_setprio(1);
    acc_a = __builtin_amdgcn_mfma_f32_32x32x16_bf16(A1.v, V1.v, acc_a, 0, 0, 0);
    acc_b = __builtin_amdgcn_mfma_f32_32x32x16_bf16(A2.v, V2.v, acc_b, 0, 0, 0);
    __builtin_amdgcn_s_setprio(0);
  }
  if (l31 < 17) {
#pragma unroll
    for (int r = 0; r < 16; ++r) {
      const int row = (r & 3) + ((r >> 2) << 3) + (h << 2);
      R[w][row][l31] = acc_a[r] + acc_b[r];
    }
  }
  __syncthreads();
  float* Rf = &R[0][0][0];
  if (tid < 544) {
    float s0 = 0.f;
#pragma unroll
    for (int w2 = 0; w2 < 16; ++w2) s0 += Rf[w2 * 544 + tid];
    Rf[tid] = s0;
  }
  __syncthreads();
  if (tid < 512) {
    const int row = tid >> 4;
    const int o0 = (tid & 15) << 1, o1 = o0 + 1;
    const float inv = 1.0f / Rf[row * 17 + 16];
    float d0 = 0.f, d1 = 0.f;
#pragma unroll
    for (int c = 0; c < 16; ++c) {
      const float cv = Rf[row * 17 + c];
      d0 += wo[o0 * 16 + c] * cv;
      d1 += wo[o1 * 16 + c] * cv;
    }
    const float y0 = fmaxf(bo[o0] + so[o0] * d0 * inv, 0.f);
    const float y1 = fmaxf(bo[o1] + so[o1] * d1 * inv, 0.f);
    *(u32*)(fus + (((qb << 5) + row) << 6) + 32 + o0) = pk_bf16(y0, y1);
  }
}

// =============== K3: 3x3x3 conv, 54 work-units (tap x K-half) over 8 waves + LDS reduce ===============
// 256 blocks x 512 threads: 2 blocks/CU -> 4 waves/SIMD; 1-deep B prefetch.
__global__ __launch_bounds__(512) void k_conv(
    const u16* __restrict__ fus, const u16* __restrict__ wrep,
    const float* __restrict__ bbot, float* __restrict__ out) {
  __shared__ float R8[8][1024];
  const int tid = threadIdx.x;
  const int wv = tid >> 6, lane = tid & 63;
  const int l31 = lane & 31, h = lane >> 5;
  const int n0 = blockIdx.x << 5;
  const int dz = n0 >> 9, hy = (n0 >> 5) & 15;
  f32x16 acc0, acc1;
#pragma unroll
  for (int i = 0; i < 16; ++i) { acc0[i] = 0.f; acc1[i] = 0.f; }
  const int ulo = (wv * 54) >> 3, uhi = ((wv + 1) * 54) >> 3;  // 6-7 units/wave

  const u16* bp_c; const u16* wp_c; bool ok_c;
  {
    const int tap = ulo >> 1, ch = (ulo & 1) << 1;
    const int dd = tap / 9 - 1, dh = (tap / 3) % 3 - 1, dw = tap % 3 - 1;
    ok_c = ((unsigned)(dz + dd) < 16u) & ((unsigned)(hy + dh) < 16u) &
           ((unsigned)(l31 + dw) < 32u);
    const int nn = n0 + dd * 512 + dh * 32 + dw + l31;
    bp_c = fus + (nn << 6) + (ch << 4) + (h << 3);
    wp_c = wrep + ((tap * 32 + l31) << 6) + (ch << 4) + (h << 3);
  }
  BF8 B0c, B1c;
  B0c.w[0] = B0c.w[1] = B0c.w[2] = B0c.w[3] = 0u;
  B1c.w[0] = B1c.w[1] = B1c.w[2] = B1c.w[3] = 0u;
  if (ok_c) { B0c.v = *(const bf16x8*)bp_c; B1c.v = *(const bf16x8*)(bp_c + 16); }

  for (int u = ulo; u < uhi; ++u) {
    const BF8 B0 = B0c, B1 = B1c;
    const u16* wp = wp_c;
    if (u + 1 < uhi) {
      const int un = u + 1;
      const int tap = un >> 1, ch = (un & 1) << 1;
      const int dd = tap / 9 - 1, dh = (tap / 3) % 3 - 1, dw = tap % 3 - 1;
      const bool ok = ((unsigned)(dz + dd) < 16u) & ((unsigned)(hy + dh) < 16u) &
                      ((unsigned)(l31 + dw) < 32u);
      const int nn = n0 + dd * 512 + dh * 32 + dw + l31;
      const u16* bp = fus + (nn << 6) + (ch << 4) + (h << 3);
      wp_c = wrep + ((tap * 32 + l31) << 6) + (ch << 4) + (h << 3);
      B0c.w[0] = B0c.w[1] = B0c.w[2] = B0c.w[3] = 0u;
      B1c.w[0] = B1c.w[1] = B1c.w[2] = B1c.w[3] = 0u;
      if (ok) { B0c.v = *(const bf16x8*)bp; B1c.v = *(const bf16x8*)(bp + 16); }
    }
    const bf16x8 af0 = *(const bf16x8*)wp;
    const bf16x8 af1 = *(const bf16x8*)(wp + 16);
    __builtin_amdgcn_s_setprio(1);
    acc0 = __builtin_amdgcn_mfma_f32_32x32x16_bf16(af0, B0.v, acc0, 0, 0, 0);
    acc1 = __builtin_amdgcn_mfma_f32_32x32x16_bf16(af1, B1.v, acc1, 0, 0, 0);
    __builtin_amdgcn_s_setprio(0);
  }
#pragma unroll
  for (int r = 0; r < 16; ++r) {
    const int row = (r & 3) + ((r >> 2) << 3) + (h << 2);
    R8[wv][(row << 5) + l31] = acc0[r] + acc1[r];
  }
  __syncthreads();
#pragma unroll
  for (int k2 = 0; k2 < 2; ++k2) {
    const int e = tid + (k2 << 9);
    const int row = e >> 5;
    float yv = bbot[row];
#pragma unroll
    for (int w2 = 0; w2 < 8; ++w2) yv += R8[w2][e];
    out[(row << 13) + n0 + (e & 31)] = yv > 0.f ? yv : 0.1f * yv;
  }
}

extern "C" void kernel_launch(void* const* d_in, const int* in_sizes, int n_in,
                              void* d_out, int out_size, void* d_ws, size_t ws_size,
                              hipStream_t stream) {
  const float* x    = (const float*)d_in[0];
  const float* wq1  = (const float*)d_in[1];
  const float* sq1  = (const float*)d_in[2];
  const float* bq1  = (const float*)d_in[3];
  const float* wq2  = (const float*)d_in[4];
  const float* sq2  = (const float*)d_in[5];
  const float* bq2  = (const float*)d_in[6];
  const float* wk1  = (const float*)d_in[7];
  const float* sk1  = (const float*)d_in[8];
  const float* bk1  = (const float*)d_in[9];
  const float* wk2  = (const float*)d_in[10];
  const float* sk2  = (const float*)d_in[11];
  const float* bk2  = (const float*)d_in[12];
  const float* wv   = (const float*)d_in[13];
  const float* sv   = (const float*)d_in[14];
  const float* bv   = (const float*)d_in[15];
  const float* wo   = (const float*)d_in[16];
  const float* so   = (const float*)d_in[17];
  const float* bo   = (const float*)d_in[18];
  const float* wbot = (const float*)d_in[19];
  const float* sbot = (const float*)d_in[20];
  const float* bbot = (const float*)d_in[21];
  (void)in_sizes; (void)n_in; (void)out_size; (void)ws_size;

  char* wsb = (char*)d_ws;
  u16* wrep = (u16*)(wsb + WB_WREP);
  u16* qs   = (u16*)(wsb + WB_QS);
  u16* kbm  = (u16*)(wsb + WB_K);
  u16* vts  = (u16*)(wsb + WB_VTS);
  u16* fus  = (u16*)(wsb + WB_FUS);
  float* out = (float*)d_out;

  k_prep<<<270, 512, 0, stream>>>(x, wq1, sq1, bq1, wq2, sq2, bq2,
                                  wk1, sk1, bk1, wk2, sk2, bk2,
                                  wv, sv, bv, wbot, sbot,
                                  qs, kbm, vts, fus, wrep);
  k_attn<<<256, 1024, 0, stream>>>(qs, kbm, vts, wo, so, bo, fus);
  k_conv<<<256, 512, 0, stream>>>(fus, wrep, bbot, out);
}